// Round 2
// baseline (194.364 us; speedup 1.0000x reference)
//
#include <hip/hip_runtime.h>

// PositionwiseMaxPool2D: x [32,128,128,64] f32 NHWC, 2x2/stride2 window.
// Per output (b,oh,ow): k* = argmax_k sum_c x[window k][c]^2 (first-wins),
// out[b,oh,ow,:] = x[winning cell][:].
//
// R1: one wave handles FOUR adjacent output-pairs (8 outputs = 16 input
// w-positions). All 8 coalesced 1KiB row-segment loads are issued up front
// (vmcnt-staged by the compiler) for 4x the memory-level parallelism of R0,
// and the index math is amortized over 8 outputs.

#define IB 32
#define IH 128
#define IW 128
#define IC 64
#define OH 64
#define OW 64

__global__ __launch_bounds__(256) void pos_maxpool_kernel(
    const float* __restrict__ x, float* __restrict__ out) {
  const int tid = threadIdx.x;
  const int l = tid & 63;                          // lane
  const int wid = (blockIdx.x << 2) + (tid >> 6);  // wave id, [0, 16384)

  // wave -> (b, oh, group g of 4 output-pairs). 8 groups per output row.
  const int g = wid & 7;
  const int t = wid >> 3;
  const int oh = t & 63;
  const int b = t >> 6;

  const int h0 = oh * 2;
  const int w0 = g * 16;  // 16 input w-positions covered by this wave

  // row segments: 16 w-positions * 64 ch = 1024 floats = 256 float4 per row
  const long long row0 = (((long long)(b * IH + h0) * IW) + w0) * IC;
  const long long row1 = row0 + (long long)IW * IC;

  const float4* __restrict__ x4 = (const float4*)x;
  const float4* p0 = x4 + (row0 >> 2) + l;
  const float4* p1 = x4 + (row1 >> 2) + l;

  // Issue all 8 loads up front (each: 64 lanes x 16B = 1 KiB coalesced).
  float4 a0[4], a1[4];
#pragma unroll
  for (int q = 0; q < 4; ++q) a0[q] = p0[q * 64];
#pragma unroll
  for (int q = 0; q < 4; ++q) a1[q] = p1[q * 64];

  const int p = (l >> 4) & 1;   // window column j of this lane's cell
  const int h = l >> 5;         // which output of the pair (0/1)
  const int c4 = l & 15;        // float4 index along channels
  float4* __restrict__ o4 = (float4*)out;
  const long long obase = (((long long)(b * OH + oh) * OW)) * (IC / 4);

#pragma unroll
  for (int q = 0; q < 4; ++q) {
    float s0 = a0[q].x * a0[q].x + a0[q].y * a0[q].y + a0[q].z * a0[q].z +
               a0[q].w * a0[q].w;
    float s1 = a1[q].x * a1[q].x + a1[q].y * a1[q].y + a1[q].z * a1[q].z +
               a1[q].w * a1[q].w;

    // channel-sum within each 16-lane group (butterfly keeps groups uniform)
#pragma unroll
    for (int off = 1; off < 16; off <<= 1) {
      s0 += __shfl_xor(s0, off, 64);
      s1 += __shfl_xor(s1, off, 64);
    }
    // partner column's norms (group ^ 1, same wave half)
    const float o0 = __shfl_xor(s0, 16, 64);
    const float o1 = __shfl_xor(s1, 16, 64);

    const float n00 = p ? o0 : s0;  // (i=0, j=0)
    const float n01 = p ? s0 : o0;  // (i=0, j=1)
    const float n10 = p ? o1 : s1;  // (i=1, j=0)
    const float n11 = p ? s1 : o1;  // (i=1, j=1)

    // argmax over k = i*2 + j, strict > == jnp.argmax first-occurrence
    int k = 0;
    float best = n00;
    if (n01 > best) { best = n01; k = 1; }
    if (n10 > best) { best = n10; k = 2; }
    if (n11 > best) { best = n11; k = 3; }
    const int istar = k >> 1;
    const int jstar = k & 1;

    // winning column's lanes store their already-loaded float4
    // (two contiguous 256B chunks per wave per q)
    if (p == jstar) {
      const int ow = (g * 4 + q) * 2 + h;
      const float4 v = istar ? a1[q] : a0[q];
      o4[obase + (long long)ow * (IC / 4) + c4] = v;
    }
  }
}

extern "C" void kernel_launch(void* const* d_in, const int* in_sizes, int n_in,
                              void* d_out, int out_size, void* d_ws,
                              size_t ws_size, hipStream_t stream) {
  const float* x = (const float*)d_in[0];
  float* out = (float*)d_out;
  // 16384 waves total = 4096 blocks x 4 waves
  pos_maxpool_kernel<<<4096, 256, 0, stream>>>(x, out);
}